// Round 4
// baseline (1013.274 us; speedup 1.0000x reference)
//
#include <hip/hip_runtime.h>

// ---------------------------------------------------------------------------
// Mask-RCNN RoI head. Round 11:
//  - roi_align7/14 were VMEM-issue-bound (1.29 VMEM instr/cyc/CU > 1.0 TA
//    ceiling; only 34% HBM BW). Replace 8 scattered float2 gathers per
//    pixel-channel with 4 float4 row loads (the 2 x-subsample bilinear pairs
//    span <=4-5 consecutive floats) + rare predicated float2 for wide boxes.
//    Element extraction via thread-uniform cndmask selects.
//  - GEMM/conv/deconv pipeline unchanged from round 10 (counted-vmcnt T3/T4).
// ---------------------------------------------------------------------------

#define NUM_CLASSES 81
#define CDIM 256
#define RTOT 1024
#define RMASK 256
#define LOG1000_16 4.135166556742356f

typedef _Float16 half8v __attribute__((ext_vector_type(8)));
typedef _Float16 half4v __attribute__((ext_vector_type(4)));
typedef float    float4v __attribute__((ext_vector_type(4)));
typedef float    float2a4 __attribute__((ext_vector_type(2), aligned(4)));
typedef float    float4a4 __attribute__((ext_vector_type(4), aligned(4)));

__device__ __forceinline__ void gload_lds16(const void* g, void* l) {
    __builtin_amdgcn_global_load_lds(
        (const __attribute__((address_space(1))) void*)g,
        (__attribute__((address_space(3))) void*)l, 16, 0, 0);
}

// ---------------------------------------------------------------------------
// K1: roi_align out_size=7 -> bf fp16 hi/lo planes (1024 x 12544 each).
// 4 float4 row loads per pixel-channel (VMEM-issue optimized).
// ---------------------------------------------------------------------------
__global__ __launch_bounds__(256) void roi_align7_kernel(
    const float* __restrict__ f0, const float* __restrict__ f1,
    const float* __restrict__ f2, const float* __restrict__ f3,
    const float* __restrict__ props, const int* __restrict__ bidx,
    _Float16* __restrict__ bf_h, _Float16* __restrict__ bf_l)
{
    int r  = blockIdx.x;
    int cg = blockIdx.y;          // 4 groups of 64 channels
    int t = threadIdx.x;
    if (t >= 196) return;
    int p  = t % 49;
    int cl = t / 49;              // 4 channel lanes
    int oy = p / 7, ox = p % 7;

    float x1 = props[r*4+0], y1 = props[r*4+1];
    float x2 = props[r*4+2], y2 = props[r*4+3];
    float area = fmaxf(x2-x1, 0.f) * fmaxf(y2-y1, 0.f);
    float lf = floorf(4.f + log2f(sqrtf(area)/224.f + 1e-6f));
    lf = fminf(fmaxf(lf, 2.f), 5.f);
    int lvl = (int)lf - 2;

    const float* feat; int H, W; float scale;
    if (lvl == 0)      { feat = f0; H = 200; W = 200; scale = 0.25f; }
    else if (lvl == 1) { feat = f1; H = 100; W = 100; scale = 0.125f; }
    else if (lvl == 2) { feat = f2; H = 50;  W = 50;  scale = 0.0625f; }
    else               { feat = f3; H = 25;  W = 25;  scale = 0.03125f; }
    int b = bidx[r];

    float x1s = x1*scale, y1s = y1*scale;
    float rw = fmaxf(x2*scale - x1s, 1.f);
    float rh = fmaxf(y2*scale - y1s, 1.f);

    // y taps: rows ya0,ya0+1 (sy=0) and yb0,yb0+1 (sy=1), weights uy[4]
    float uy[4]; int ya0 = 0, yb0 = 0;
    #pragma unroll
    for (int sy = 0; sy < 2; ++sy) {
        int iy = oy*2 + sy;
        float gy = ((float)iy + 0.5f) / 14.f;
        float yc = y1s + rh*gy;
        float mv = ((yc > -1.f) && (yc < (float)H)) ? 1.f : 0.f;
        float ycl = fminf(fmaxf(yc, 0.f), (float)(H-1));
        int   y0  = (int)fminf(floorf(ycl), (float)(H-2));
        float ly  = ycl - (float)y0;
        if (sy == 0) { ya0 = y0; uy[0] = (1.f-ly)*mv; uy[1] = ly*mv; }
        else         { yb0 = y0; uy[2] = (1.f-ly)*mv; uy[3] = ly*mv; }
    }
    // x taps: cols xa0,xa0+1 (sx=0) and xb0,xb0+1 (sx=1), weights wx[4]
    float wx[4]; int xa0 = 0, xb0 = 0;
    #pragma unroll
    for (int sx = 0; sx < 2; ++sx) {
        int ix = ox*2 + sx;
        float gx = ((float)ix + 0.5f) / 14.f;
        float xc = x1s + rw*gx;
        float mv = ((xc > -1.f) && (xc < (float)W)) ? 1.f : 0.f;
        float xcl = fminf(fmaxf(xc, 0.f), (float)(W-1));
        int   x0  = (int)fminf(floorf(xcl), (float)(W-2));
        float lx  = xcl - (float)x0;
        if (sx == 0) { xa0 = x0; wx[0] = (1.f-lx)*mv; wx[1] = lx*mv; }
        else         { xb0 = x0; wx[2] = (1.f-lx)*mv; wx[3] = lx*mv; }
    }
    int xm = min(xa0, W-4);       // float4 base, always in-bounds
    int sa = xa0 - xm;            // 0..2
    int sb = xb0 - xm;            // 0.. (rarely >2)
    bool ex = (sb > 2);
    int rws[4] = {ya0, ya0+1, yb0, yb0+1};

    size_t HW = (size_t)H * W;
    #pragma unroll 4
    for (int k = 0; k < 16; ++k) {
        int c = cg*64 + cl + k*4;
        const float* fb = feat + ((size_t)b*CDIM + c) * HW;
        float acc = 0.f;
        #pragma unroll
        for (int rr = 0; rr < 4; ++rr) {
            const float* rp = fb + rws[rr]*W;
            float4a4 f = *(const float4a4*)(rp + xm);
            float va0 = (sa==0) ? f.x : ((sa==1) ? f.y : f.z);
            float va1 = (sa==0) ? f.y : ((sa==1) ? f.z : f.w);
            float vb0, vb1;
            if (ex) {
                float2a4 e = *(const float2a4*)(rp + xb0);
                vb0 = e.x; vb1 = e.y;
            } else {
                vb0 = (sb==0) ? f.x : ((sb==1) ? f.y : f.z);
                vb1 = (sb==0) ? f.y : ((sb==1) ? f.z : f.w);
            }
            acc += uy[rr]*(wx[0]*va0 + wx[1]*va1 + wx[2]*vb0 + wx[3]*vb1);
        }
        float v = acc * 0.25f;
        _Float16 h = (_Float16)v;
        size_t o = (size_t)r*12544 + c*49 + p;
        bf_h[o] = h;
        bf_l[o] = (_Float16)((v - (float)h) * 2048.f);
    }
}

// ---------------------------------------------------------------------------
// K2/K3/K4: split-fp16 MFMA GEMM. BM=128 x BN=128, BK=32, 4 waves (2Mx2N),
// wave tile 64x64. Counted-vmcnt pipeline: 3 LDS buffers, DMA depth 2,
// raw s_barrier (no vmcnt(0) drain). 8 VMEM per wave per tile, uniform.
// BMODE 0: B fp32 via DMA + bit-identical split on read (fc1).
// BMODE 1: B pre-split fp16 h/l via DMA (fc2 / heads).
// ---------------------------------------------------------------------------
template<int BMODE>
__global__ __launch_bounds__(256, 1) void gemm_fc2(
    const _Float16* __restrict__ Ah, const _Float16* __restrict__ Al,
    const float* __restrict__ B32,
    const _Float16* __restrict__ Bh16, const _Float16* __restrict__ Bl16,
    float* __restrict__ Cp, int K, int KS, int NS)
{
    __shared__ __align__(16) char smem[3*32768];

    int t = threadIdx.x;
    int lane = t & 63, wave = t >> 6;
    int wm = wave >> 1, wn = wave & 1;
    int ln = lane & 15, q = lane >> 4;

    // XCD-aware bijective block swizzle (total blocks % 8 == 0)
    int gx = gridDim.x, gy = gridDim.y;
    int lin = blockIdx.x + gx*(blockIdx.y + gy*blockIdx.z);
    int per = (gx*gy*(int)gridDim.z) >> 3;
    int nl  = (lin & 7)*per + (lin >> 3);
    int bn  = nl % gx;
    int tmp = nl / gx;
    int bm  = tmp % gy;
    int kz  = tmp / gy;

    size_t kbase = (size_t)kz * KS;
    int asub = lane >> 2;                        // row within 16-row group
    int achk = (lane & 3) ^ ((lane >> 3) & 3);   // pre-swizzled 16B chunk (4/row)

    const _Float16* Agh0 = Ah + (size_t)(bm*128 + wave*32 + asub)*K + kbase + achk*8;
    const _Float16* Agh1 = Agh0 + (size_t)16*K;
    const _Float16* Agl0 = Al + (size_t)(bm*128 + wave*32 + asub)*K + kbase + achk*8;
    const _Float16* Agl1 = Agl0 + (size_t)16*K;
    int adst0 = (wave*32 + 0)*32;
    int adst1 = (wave*32 + 16)*32;

    const _Float16 *Bgh0=nullptr, *Bgh1=nullptr, *Bgl0=nullptr, *Bgl1=nullptr;
    const float *Bg0=nullptr, *Bg1=nullptr, *Bg2=nullptr, *Bg3=nullptr;
    int fdst0 = 0;
    if constexpr (BMODE == 1) {
        Bgh0 = Bh16 + (size_t)(bn*128 + wave*32 + asub)*K + kbase + achk*8;
        Bgh1 = Bgh0 + (size_t)16*K;
        Bgl0 = Bl16 + (size_t)(bn*128 + wave*32 + asub)*K + kbase + achk*8;
        Bgl1 = Bgl0 + (size_t)16*K;
    } else {
        int br8  = lane >> 3;                    // row within 8-row group
        int bchk = (lane & 7) ^ br8;             // pre-swizzled 16B chunk (8/row)
        const float* base = B32 + (size_t)(bn*128 + wave*32 + br8)*K + kbase + bchk*4;
        Bg0 = base;
        Bg1 = base + (size_t)8*K;
        Bg2 = base + (size_t)16*K;
        Bg3 = base + (size_t)24*K;
        fdst0 = (wave*32)*32;                    // floats
    }

    auto AhB = [&](int b){ return (_Float16*)(smem + b*32768); };
    auto AlB = [&](int b){ return (_Float16*)(smem + b*32768 + 8192); };
    auto BhB = [&](int b){ return (_Float16*)(smem + b*32768 + 16384); };
    auto BlB = [&](int b){ return (_Float16*)(smem + b*32768 + 24576); };
    auto BfB = [&](int b){ return (float*)   (smem + b*32768 + 16384); };

    auto dma = [&](int k0, int b) {              // 8 VMEM instrs per wave
        gload_lds16(Agh0 + k0, AhB(b) + adst0);
        gload_lds16(Agh1 + k0, AhB(b) + adst1);
        gload_lds16(Agl0 + k0, AlB(b) + adst0);
        gload_lds16(Agl1 + k0, AlB(b) + adst1);
        if constexpr (BMODE == 1) {
            gload_lds16(Bgh0 + k0, BhB(b) + adst0);
            gload_lds16(Bgh1 + k0, BhB(b) + adst1);
            gload_lds16(Bgl0 + k0, BlB(b) + adst0);
            gload_lds16(Bgl1 + k0, BlB(b) + adst1);
        } else {
            gload_lds16(Bg0 + k0, BfB(b) + fdst0);
            gload_lds16(Bg1 + k0, BfB(b) + fdst0 + 8*32);
            gload_lds16(Bg2 + k0, BfB(b) + fdst0 + 16*32);
            gload_lds16(Bg3 + k0, BfB(b) + fdst0 + 24*32);
        }
    };

    float4v acc1[4][4], acc2[4][4];
    #pragma unroll
    for (int i = 0; i < 4; ++i)
        #pragma unroll
        for (int j = 0; j < 4; ++j) {
            acc1[i][j] = (float4v){0.f,0.f,0.f,0.f};
            acc2[i][j] = (float4v){0.f,0.f,0.f,0.f};
        }

    int cq = (q ^ ((ln >> 1) & 3)) * 8;

    auto compute = [&](int b) {
        const _Float16* ah = AhB(b);
        const _Float16* al = AlB(b);
        half8v afh[4], afl[4], bfh[4], bfl[4];
        #pragma unroll
        for (int i = 0; i < 4; ++i) {
            int ra = (wm*64 + i*16 + ln)*32 + cq;
            afh[i] = *(const half8v*)&ah[ra];
            afl[i] = *(const half8v*)&al[ra];
        }
        if constexpr (BMODE == 1) {
            const _Float16* bh = BhB(b);
            const _Float16* bl = BlB(b);
            #pragma unroll
            for (int j = 0; j < 4; ++j) {
                int rb = (wn*64 + j*16 + ln)*32 + cq;
                bfh[j] = *(const half8v*)&bh[rb];
                bfl[j] = *(const half8v*)&bl[rb];
            }
        } else {
            const float* bfp = BfB(b);
            #pragma unroll
            for (int j = 0; j < 4; ++j) {
                int row = wn*64 + j*16 + ln;
                int c0 = (q*2)   ^ (row & 7);
                int c1 = (q*2+1) ^ (row & 7);
                float4v f0 = *(const float4v*)&bfp[row*32 + c0*4];
                float4v f1 = *(const float4v*)&bfp[row*32 + c1*4];
                #pragma unroll
                for (int e = 0; e < 4; ++e) {
                    _Float16 h0 = (_Float16)f0[e];
                    bfh[j][e] = h0;
                    bfl[j][e] = (_Float16)((f0[e] - (float)h0) * 2048.f);
                    _Float16 h1 = (_Float16)f1[e];
                    bfh[j][4+e] = h1;
                    bfl[j][4+e] = (_Float16)((f1[e] - (float)h1) * 2048.f);
                }
            }
        }
        #pragma unroll
        for (int i = 0; i < 4; ++i) {
            #pragma unroll
            for (int j = 0; j < 4; ++j) {
                acc1[i][j] = __builtin_amdgcn_mfma_f32_16x16x32_f16(
                    afh[i], bfh[j], acc1[i][j], 0, 0, 0);
                acc2[i][j] = __builtin_amdgcn_mfma_f32_16x16x32_f16(
                    afh[i], bfl[j], acc2[i][j], 0, 0, 0);
                acc2[i][j] = __builtin_amdgcn_mfma_f32_16x16x32_f16(
                    afl[i], bfh[j], acc2[i][j], 0, 0, 0);
            }
        }
    };

    int NT = KS / 32;
    dma(0, 0);
    if (NT > 1) dma(32, 1);

    for (int tt = 0; tt < NT; ++tt) {
        if (tt < NT-1) asm volatile("s_waitcnt vmcnt(8)" ::: "memory");
        else           asm volatile("s_waitcnt vmcnt(0)" ::: "memory");
        __builtin_amdgcn_s_barrier();
        asm volatile("" ::: "memory");
        if (tt + 2 < NT) dma((tt+2)*32, (tt+2)%3);
        compute(tt%3);
    }

    float* Cpz = Cp + (size_t)kz*1024*NS;
    #pragma unroll
    for (int i = 0; i < 4; ++i) {
        #pragma unroll
        for (int j = 0; j < 4; ++j) {
            int col = bn*128 + wn*64 + j*16 + ln;
            #pragma unroll
            for (int reg = 0; reg < 4; ++reg) {
                int row = bm*128 + wm*64 + i*16 + q*4 + reg;
                Cpz[(size_t)row*NS + col] =
                    acc1[i][j][reg] + acc2[i][j][reg] * (1.f/2048.f);
            }
        }
    }
}

// reduce nparts split-K partials + bias (+optional relu).
__global__ __launch_bounds__(256) void fc_reduce_kernel(
    const float* __restrict__ Cp, const float* __restrict__ bias,
    float* __restrict__ out, _Float16* __restrict__ outh,
    _Float16* __restrict__ outl, int nparts, int ns4, int do_relu)
{
    int i = blockIdx.x*256 + threadIdx.x;
    const float4* p = (const float4*)Cp;
    int pstride = 1024*ns4;
    float sx = 0.f, sy = 0.f, sz = 0.f, sw = 0.f;
    for (int j = 0; j < nparts; ++j) {
        float4 s = p[i + j*pstride];
        sx += s.x; sy += s.y; sz += s.z; sw += s.w;
    }
    float4 b4 = ((const float4*)bias)[i & (ns4-1)];
    float4 v;
    v.x = sx + b4.x; v.y = sy + b4.y; v.z = sz + b4.z; v.w = sw + b4.w;
    if (do_relu) {
        v.x = fmaxf(v.x, 0.f); v.y = fmaxf(v.y, 0.f);
        v.z = fmaxf(v.z, 0.f); v.w = fmaxf(v.w, 0.f);
    }
    if (out) ((float4*)out)[i] = v;
    if (outh) {
        float vv[4] = {v.x, v.y, v.z, v.w};
        half4v hh, hl;
        #pragma unroll
        for (int c2 = 0; c2 < 4; ++c2) {
            _Float16 h = (_Float16)vv[c2];
            hh[c2] = h;
            hl[c2] = (_Float16)((vv[c2] - (float)h) * 2048.f);
        }
        ((half4v*)outh)[i] = hh;
        ((half4v*)outl)[i] = hl;
    }
}

// generic fp32 -> fp16 h/l pre-split (bit-identical to in-GEMM split)
__global__ __launch_bounds__(256) void repack_split_kernel(
    const float* __restrict__ w, _Float16* __restrict__ h,
    _Float16* __restrict__ l)
{
    int i = blockIdx.x*256 + threadIdx.x;
    float4 v = ((const float4*)w)[i];
    float vv[4] = {v.x, v.y, v.z, v.w};
    half4v hh, hl;
    #pragma unroll
    for (int c2 = 0; c2 < 4; ++c2) {
        _Float16 hj = (_Float16)vv[c2];
        hh[c2] = hj;
        hl[c2] = (_Float16)((vv[c2] - (float)hj) * 2048.f);
    }
    ((half4v*)h)[i] = hh;
    ((half4v*)l)[i] = hl;
}

// ---------------------------------------------------------------------------
// Head weight concat, pre-split fp16 hi/lo.
// ---------------------------------------------------------------------------
__global__ __launch_bounds__(256) void repack_head_kernel(
    const float* __restrict__ cls_w, const float* __restrict__ cls_b,
    const float* __restrict__ bbox_w, const float* __restrict__ bbox_b,
    _Float16* __restrict__ Wcat_h, _Float16* __restrict__ Wcat_l,
    float* __restrict__ bcat)
{
    int i = blockIdx.x*256 + threadIdx.x;    // 512*1024
    int row = i >> 10, col = i & 1023;
    float v = 0.f;
    if (row < 81) v = cls_w[row*1024 + col];
    else if (row < 405) v = bbox_w[(row-81)*1024 + col];
    _Float16 h = (_Float16)v;
    Wcat_h[i] = h;
    Wcat_l[i] = (_Float16)((v - (float)h) * 2048.f);
    if (i < 512) {
        float bv = 0.f;
        if (i < 81) bv = cls_b[i];
        else if (i < 405) bv = bbox_b[i-81];
        bcat[i] = bv;
    }
}

// ---------------------------------------------------------------------------
// heads_finish: softmax/argmax/decode from precomputed L[1024][512].
// ---------------------------------------------------------------------------
__global__ __launch_bounds__(128) void heads_finish_kernel(
    const float* __restrict__ L, const float* __restrict__ props,
    float* __restrict__ scores, float* __restrict__ boxes,
    int* __restrict__ labels, float* __restrict__ mboxes)
{
    __shared__ float lg[NUM_CLASSES];
    __shared__ float red[2];
    __shared__ int slab;
    int r = blockIdx.x, t = threadIdx.x;
    const float* Lr = L + (size_t)r*512;
    if (t < NUM_CLASSES) lg[t] = Lr[t];
    __syncthreads();
    if (t == 0) {
        float mx = lg[0];
        for (int j = 1; j < NUM_CLASSES; ++j) mx = fmaxf(mx, lg[j]);
        red[0] = mx;
    }
    __syncthreads();
    float mx = red[0];
    if (t < NUM_CLASSES) lg[t] = expf(lg[t] - mx);
    __syncthreads();
    if (t == 0) {
        float s = 0.f;
        int best = 1; float bv = lg[1];
        for (int j = 0; j < NUM_CLASSES; ++j) {
            s += lg[j];
            if (j >= 1 && lg[j] > bv) { bv = lg[j]; best = j; }
        }
        red[1] = 1.f/s;
        slab = best;
    }
    __syncthreads();
    if (t < NUM_CLASSES) scores[(size_t)r*NUM_CLASSES + t] = lg[t]*red[1];

    bool sel = (r < 128) || (r >= 512 && r < 640);
    int mi = (r < 128) ? r : r - 384;
    if (t == 0 && sel) labels[mi] = slab;

    if (t < NUM_CLASSES) {
        float px1 = props[r*4+0], py1 = props[r*4+1];
        float px2 = props[r*4+2], py2 = props[r*4+3];
        float pw = px2 - px1, ph = py2 - py1;
        float cx = px1 + 0.5f*pw, cy = py1 + 0.5f*ph;
        const float* dl = Lr + 81 + t*4;
        float d0 = dl[0] * 0.1f;
        float d1 = dl[1] * 0.1f;
        float d2 = fminf(dl[2] * 0.2f, LOG1000_16);
        float d3 = fminf(dl[3] * 0.2f, LOG1000_16);
        float pcx = d0*pw + cx, pcy = d1*ph + cy;
        float qw = expf(d2)*pw, qh = expf(d3)*ph;
        float b0 = fminf(fmaxf(pcx - 0.5f*qw, 0.f), 800.f);
        float b1 = fminf(fmaxf(pcy - 0.5f*qh, 0.f), 800.f);
        float b2 = fminf(fmaxf(pcx + 0.5f*qw, 0.f), 800.f);
        float b3 = fminf(fmaxf(pcy + 0.5f*qh, 0.f), 800.f);
        size_t ob = ((size_t)r*NUM_CLASSES + t)*4;
        boxes[ob+0] = b0; boxes[ob+1] = b1; boxes[ob+2] = b2; boxes[ob+3] = b3;
        if (sel && t == slab) {
            mboxes[mi*4+0] = b0; mboxes[mi*4+1] = b1;
            mboxes[mi*4+2] = b2; mboxes[mi*4+3] = b3;
        }
    }
}

// ---------------------------------------------------------------------------
// K6: roi_align 14x14 -> transposed fp16 actT[mi][p][c]. float4 row loads.
// ---------------------------------------------------------------------------
__global__ __launch_bounds__(256) void roi_align14_kernel(
    const float* __restrict__ f0, const float* __restrict__ f1,
    const float* __restrict__ f2, const float* __restrict__ f3,
    const float* __restrict__ mboxes, const int* __restrict__ bidx,
    _Float16* __restrict__ outT)
{
    int mi = blockIdx.x;
    int cg = blockIdx.y;          // 8 groups of 32 channels
    int t = threadIdx.x;
    if (t >= 196) return;
    int oy = t / 14, ox = t % 14;

    float x1 = mboxes[mi*4+0], y1 = mboxes[mi*4+1];
    float x2 = mboxes[mi*4+2], y2 = mboxes[mi*4+3];
    float area = fmaxf(x2-x1, 0.f) * fmaxf(y2-y1, 0.f);
    float lf = floorf(4.f + log2f(sqrtf(area)/224.f + 1e-6f));
    lf = fminf(fmaxf(lf, 2.f), 5.f);
    int lvl = (int)lf - 2;

    const float* feat; int H, W; float scale;
    if (lvl == 0)      { feat = f0; H = 200; W = 200; scale = 0.25f; }
    else if (lvl == 1) { feat = f1; H = 100; W = 100; scale = 0.125f; }
    else if (lvl == 2) { feat = f2; H = 50;  W = 50;  scale = 0.0625f; }
    else               { feat = f3; H = 25;  W = 25;  scale = 0.03125f; }
    int ridx = (mi < 128) ? mi : mi + 384;
    int b = bidx[ridx];

    float x1s = x1*scale, y1s = y1*scale;
    float rw = fmaxf(x2*scale - x1s, 1.f);
    float rh = fmaxf(y2*scale - y1s, 1.f);

    float uy[4]; int ya0 = 0, yb0 = 0;
    #pragma unroll
    for (int sy = 0; sy < 2; ++sy) {
        int iy = oy*2 + sy;
        float gy = ((float)iy + 0.5f) / 28.f;
        float yc = y1s + rh*gy;
        float mv = ((yc > -1.f) && (yc < (float)H)) ? 1.f : 0.f;
        float ycl = fminf(fmaxf(yc, 0.f), (float)(H-1));
        int   y0  = (int)fminf(floorf(ycl), (float)(H-2));
        float ly  = ycl - (float)y0;
        if (sy == 0) { ya0 = y0; uy[0] = (1.f-ly)*mv; uy[1] = ly*mv; }
        else         { yb0 = y0; uy[2] = (1.f-ly)*mv; uy[3] = ly*mv; }
    }
    float wx[4]; int xa0 = 0, xb0 = 0;
    #pragma unroll
    for (int sx = 0; sx < 2; ++sx) {
        int ix = ox*2 + sx;
        float gx = ((float)ix + 0.5f) / 28.f;
        float xc = x1s + rw*gx;
        float mv = ((xc > -1.f) && (xc < (float)W)) ? 1.f : 0.f;
        float xcl = fminf(fmaxf(xc, 0.f), (float)(W-1));
        int   x0  = (int)fminf(floorf(xcl), (float)(W-2));
        float lx  = xcl - (float)x0;
        if (sx == 0) { xa0 = x0; wx[0] = (1.f-lx)*mv; wx[1] = lx*mv; }
        else         { xb0 = x0; wx[2] = (1.f-lx)*mv; wx[3] = lx*mv; }
    }
    int xm = min(xa0, W-4);
    int sa = xa0 - xm;
    int sb = xb0 - xm;
    bool ex = (sb > 2);
    int rws[4] = {ya0, ya0+1, yb0, yb0+1};

    size_t HW = (size_t)H * W;
    _Float16* orow = outT + ((size_t)mi*196 + t)*CDIM + cg*32;
    const float* fbase = feat + ((size_t)b*CDIM + cg*32) * HW;
    #pragma unroll
    for (int c8 = 0; c8 < 32; c8 += 8) {
        half8v hv;
        #pragma unroll
        for (int cc = 0; cc < 8; ++cc) {
            const float* fb = fbase + (size_t)(c8+cc) * HW;
            float acc = 0.f;
            #pragma unroll
            for (int rr = 0; rr < 4; ++rr) {
                const float* rp = fb + rws[rr]*W;
                float4a4 f = *(const float4a4*)(rp + xm);
                float va0 = (sa==0) ? f.x : ((sa==1) ? f.y : f.z);
                float va1 = (sa==0) ? f.y : ((sa==1) ? f.z : f.w);
                float vb0, vb1;
                if (ex) {
                    float2a4 e = *(const float2a4*)(rp + xb0);
                    vb0 = e.x; vb1 = e.y;
                } else {
                    vb0 = (sb==0) ? f.x : ((sb==1) ? f.y : f.z);
                    vb1 = (sb==0) ? f.y : ((sb==1) ? f.z : f.w);
                }
                acc += uy[rr]*(wx[0]*va0 + wx[1]*va1 + wx[2]*vb0 + wx[3]*vb1);
            }
            hv[cc] = (_Float16)(acc * 0.25f);
        }
        *(half8v*)(orow + c8) = hv;
    }
}

// ---------------------------------------------------------------------------
// Weight repacks (conv / deconv)
// ---------------------------------------------------------------------------
__global__ __launch_bounds__(256) void repack_wts_kernel(
    const float* __restrict__ w, _Float16* __restrict__ Wr)
{
    int i = blockIdx.x*256 + threadIdx.x;   // 4*9*256*256
    int ci = i & 255;
    int rest = i >> 8;
    int co = rest & 255;
    int rest2 = rest >> 8;
    int tap = rest2 % 9;
    int l = rest2 / 9;
    Wr[i] = (_Float16)w[(((size_t)(l*256 + co)*256 + ci)*9) + tap];
}

__global__ __launch_bounds__(256) void repack_dw_kernel(
    const float* __restrict__ dw, _Float16* __restrict__ Wd)
{
    int i = blockIdx.x*256 + threadIdx.x;   // 1024*256
    int n = i >> 8, k = i & 255;
    Wd[i] = (_Float16)dw[(size_t)k*1024 + n];
}

// ---------------------------------------------------------------------------
// K7: conv3x3+bias+relu as fp16 MFMA implicit GEMM, 2 co-tiles per wave.
// ---------------------------------------------------------------------------
#define PSTR 40

__global__ __launch_bounds__(256, 2) void conv3x3_mfma_kernel(
    const _Float16* __restrict__ inT, const _Float16* __restrict__ Wr,
    const float* __restrict__ bias, _Float16* __restrict__ outT, int layer)
{
    __shared__ _Float16 lin[256*PSTR];   // 20 KiB

    int t = threadIdx.x;
    int lane = t & 63;
    int wave = t >> 6;
    int ln = lane & 15;
    int q  = lane >> 4;
    int q8 = q*8;
    int r  = blockIdx.x >> 1;
    int bc = blockIdx.x & 1;
    int co_w = bc*128 + wave*32;     // wave owns 32 consecutive co

    const _Float16* WrL = Wr + (size_t)layer*9*256*256;
    const _Float16* inR = inT + (size_t)r*196*256;

    for (int i = t; i < 256*PSTR; i += 256) lin[i] = (_Float16)0.f;

    float4v acc[13][2];
    #pragma unroll
    for (int nt = 0; nt < 13; ++nt) {
        acc[nt][0] = (float4v){0.f,0.f,0.f,0.f};
        acc[nt][1] = (float4v){0.f,0.f,0.f,0.f};
    }

    for (int ci0 = 0; ci0 < 256; ci0 += 32) {
        __syncthreads();
        for (int idx = t; idx < 784; idx += 256) {
            int p = idx >> 2, g = idx & 3;
            float4 v = *(const float4*)(inR + (size_t)p*256 + ci0 + g*8);
            int row = (p*37450) >> 19;
            int col = p - row*14;
            *(float4*)&lin[((row+1)*16 + (col+1))*PSTR + g*8] = v;
        }
        __syncthreads();

        half8v aw[9][2];
        #pragma unroll
        for (int tap = 0; tap < 9; ++tap) {
            #pragma unroll
            for (int u = 0; u < 2; ++u)
                aw[tap][u] = *(const half8v*)(
                    WrL + ((size_t)tap*256 + co_w + u*16 + ln)*256 + ci0 + q8);
        }

        #pragma unroll
        for (int nt = 0; nt < 13; ++nt) {
            int n = nt*16 + ln;
            int row = (n*37450) >> 19;
            int col = n - row*14;
            int pb = (n < 196) ? (row*16 + col) : 0;
            const _Float16* bp = &lin[pb*PSTR + q8];
            #pragma unroll
            for (int ky = 0; ky < 3; ++ky) {
                #pragma unroll
                for (int kx = 0; kx < 3; ++kx) {
                    half8v bv = *(const half8v*)(bp + (ky*16 + kx)*PSTR);
                    acc[nt][0] = __builtin_amdgcn_mfma_f32_16x16x32_f16(
                        aw[ky*3+kx][0], bv, acc[nt][0], 0, 0, 0);
                    acc[nt][1] = __builtin_amdgcn_mfma_f32_16x16x32_f16(
                        aw[ky*3+kx][1], bv, acc[nt][1], 0, 0, 0);
                }
            }
        }
    }

    #pragma unroll
    for (int u = 0; u < 2; ++u) {
        float4 bi = *(const float4*)&bias[layer*256 + co_w + u*16 + q*4];
        float bia[4] = {bi.x, bi.y, bi.z, bi.w};
        #pragma unroll
        for (int nt = 0; nt < 13; ++nt) {
            int n = nt*16 + ln;
            if (n < 196) {
                half4v hv;
                #pragma unroll
                for (int i = 0; i < 4; ++i)
                    hv[i] = (_Float16)fmaxf(acc[nt][u][i] + bia[i], 0.f);
                *(half4v*)(outT + ((size_t)r*196 + n)*256 + co_w + u*16 + q*4) = hv;
            }
        }
    }
}

// ---------------------------------------------------------------------------
// K8: deconv+mask head, fp16 MFMA per-roi GEMM with fused epilogue.
// ---------------------------------------------------------------------------
#define DSTR 264   // LDS act row stride in halves (528 B, 16B-aligned)

template<int NMT>
__device__ __forceinline__ void deconv_pass(
    const _Float16* actL, const _Float16* __restrict__ Wd,
    const float* __restrict__ db, const float* __restrict__ mlw,
    int lab, float (*sred)[4], int wv, int ln, int q, int px0)
{
    float P[NMT][4];
    #pragma unroll
    for (int mt = 0; mt < NMT; ++mt)
        #pragma unroll
        for (int r2 = 0; r2 < 4; ++r2) P[mt][r2] = 0.f;

    for (int c = 0; c < 8; ++c) {
        int n0 = wv*256 + c*32;
        float4v acc[NMT][2];
        #pragma unroll
        for (int mt = 0; mt < NMT; ++mt) {
            acc[mt][0] = (float4v){0.f,0.f,0.f,0.f};
            acc[mt][1] = (float4v){0.f,0.f,0.f,0.f};
        }
        #pragma unroll
        for (int k = 0; k < 8; ++k) {
            const _Float16* wp = Wd + ((size_t)(n0 + ln))*256 + k*32 + q*8;
            half8v b0 = *(const half8v*)wp;
            half8v b1 = *(const half8v*)(wp + 16*256);
            #pragma unroll
            for (int mt = 0; mt < NMT; ++mt) {
                half8v a = *(const half8v*)&actL[(mt*16 + ln)*DSTR + k*32 + q*8];
                acc[mt][0] = __builtin_amdgcn_mfma_f32_16x16x32_f16(
                    a, b0, acc[mt][0], 0, 0, 0);
                acc[mt][1] = __builtin_amdgcn_mfma_f32_16x16x32_f16(
                    a, b1, acc[mt][1], 0, 0, 0);
            }
        }
        #pragma unroll
        for (int j = 0; j < 2; ++j) {
            int n = n0 + j*16 + ln;
            int o = n >> 2;
            float bo = db[o];
            float wl = mlw[lab*256 + o];
            #pragma unroll
            for (int mt = 0; mt < NMT; ++mt)
                #pragma unroll
                for (int r2 = 0; r2 < 4; ++r2)
                    P[mt][r2] += fmaxf(acc[mt][j][r2] + bo, 0.f) * wl;
        }
    }
    #pragma unroll
    for (int mt = 0; mt < NMT; ++mt)
        #pragma unroll
        for (int r2 = 0; r2 < 4; ++r2) {
            float v = P[mt][r2];
            v += __shfl_xor(v, 4);
            v += __shfl_xor(v, 8);
            int px = px0 + mt*16 + q*4 + r2;
            if (ln < 4 && px < 196) atomicAdd(&sred[px][ln], v);
        }
}

__global__ __launch_bounds__(256, 1) void deconv_mask_mfma_kernel(
    const _Float16* __restrict__ mfT, const _Float16* __restrict__ Wd,
    const float* __restrict__ db, const float* __restrict__ mlw,
    const float* __restrict__ mlb, const int* __restrict__ labels,
    float* __restrict__ masks)
{
    __shared__ _Float16 act[112*DSTR];   // 59136 B
    __shared__ float sred[196][4];       //  3136 B
    int t = threadIdx.x;
    int lane = t & 63, wv = t >> 6, ln = lane & 15, q = lane >> 4;
    int mi = blockIdx.x;
    int lab = labels[mi];

    for (int i = t; i < 784; i += 256) ((float*)sred)[i] = 0.f;

    for (int idx = t; idx < 112*32; idx += 256) {
        int px = idx >> 5, g = idx & 31;
        *(float4*)&act[px*DSTR + g*8] =
            *(const float4*)(mfT + ((size_t)mi*196 + px)*256 + g*8);
    }
    __syncthreads();
    deconv_pass<7>(act, Wd, db, mlw, lab, sred, wv, ln, q, 0);
    __syncthreads();

    for (int idx = t; idx < 84*32; idx += 256) {
        int px = idx >> 5, g = idx & 31;
        *(float4*)&act[px*DSTR + g*8] =
            *(const float4*)(mfT + ((size_t)mi*196 + 112 + px)*256 + g*8);
    }
    __syncthreads();
    deconv_pass<6>(act, Wd, db, mlw, lab, sred, wv, ln, q, 112);
    __syncthreads();

    if (t < 196) {
        float bl = mlb[lab];
        int i2 = t / 14, j2 = t % 14;
        #pragma unroll
        for (int pq = 0; pq < 4; ++pq) {
            float s = sred[t][pq] + bl;
            int h = 2*i2 + (pq >> 1), w2 = 2*j2 + (pq & 1);
            masks[(size_t)mi*784 + h*28 + w2] = 1.f/(1.f + expf(-s));
        }
    }
}

// ---------------------------------------------------------------------------
extern "C" void kernel_launch(void* const* d_in, const int* in_sizes, int n_in,
                              void* d_out, int out_size, void* d_ws, size_t ws_size,
                              hipStream_t stream) {
    const float* f0      = (const float*)d_in[0];
    const float* f1      = (const float*)d_in[1];
    const float* f2      = (const float*)d_in[2];
    const float* f3      = (const float*)d_in[3];
    const float* props   = (const float*)d_in[4];
    const float* fc1_w   = (const float*)d_in[5];
    const float* fc1_b   = (const float*)d_in[6];
    const float* fc2_w   = (const float*)d_in[7];
    const float* fc2_b   = (const float*)d_in[8];
    const float* cls_w   = (const float*)d_in[9];
    const float* cls_b   = (const float*)d_in[10];
    const float* bbox_w  = (const float*)d_in[11];
    const float* bbox_b  = (const float*)d_in[12];
    const float* mconv_w = (const float*)d_in[13];
    const float* mconv_b = (const float*)d_in[14];
    const float* dconv_w = (const float*)d_in[15];
    const float* dconv_b = (const float*)d_in[16];
    const float* mlog_w  = (const float*)d_in[17];
    const float* mlog_b  = (const float*)d_in[18];
    const int*   bidx    = (const int*)d_in[19];

    // workspace layout (bytes) -- max offset ~80.66 MB (unchanged budget)
    char* wsb = (char*)d_ws;
    _Float16* bf_h = (_Float16*)wsb;                 // [0, 25.69MB)
    _Float16* bf_l = (_Float16*)(wsb + 25690112);    // [25.69, 51.38MB)
    _Float16* fc2h = (_Float16*)wsb;                 // alias (bf dead post-fc1)
    _Float16* fc2l = (_Float16*)(wsb + 2097152);
    _Float16* bufA = (_Float16*)wsb;                 // alias: conv ping
    _Float16* bufB = (_Float16*)(wsb + 25690112);    // conv pong
    _Float16* x1h  = (_Float16*)(wsb + 51380224);    // 2MB
    _Float16* x1l  = (_Float16*)(wsb + 53477376);    // 2MB
    _Float16* x2h  = (_Float16*)(wsb + 55574528);    // 2MB
    _Float16* x2l  = (_Float16*)(wsb + 57671680);    // 2MB
    int*      labels = (int*)(wsb + 59768832);       // 4KB pad
    float*    mboxes = (float*)(wsb + 59772928);     // 8KB pad
    float*    Cp     = (float*)(wsb + 59781120);     // 16MB partials
    _Float16* Wr     = (_Float16*)(wsb + 59781120);  // alias Cp (after heads)
    _Float16* Wd     = (_Float16*)(wsb + 64499712);  // alias Cp (after heads)
    _Float16* Wcat_h = (_Float16*)(wsb + 76558336);  // 1MB
    _Float16* Wcat_l = (_Float16*)(wsb + 77606912);  // 1MB
    float*    bcat   = (float*)(wsb + 78655488);     // 2KB (pad to 4KB)
    float*    Lh     = (float*)(wsb + 78659584);     // 2MB logits+deltas

    float* scores = (float*)d_out;
    float* boxes  = scores + RTOT*NUM_CLASSES;
    float* masks  = boxes + RTOT*NUM_CLASSES*4;

    // K1: roi_align 7x7 -> bf hi/lo fp16 (channel-split: 4 groups)
    roi_align7_kernel<<<dim3(RTOT, 4), 256, 0, stream>>>(
        f0, f1, f2, f3, props, bidx, bf_h, bf_l);

    // head weight concat+split (independent of fc phase)
    repack_head_kernel<<<2048, 256, 0, stream>>>(cls_w, cls_b, bbox_w, bbox_b,
                                                 Wcat_h, Wcat_l, bcat);

    // K2: fc1 (A presplit DMA, B fp32 DMA + convert-on-read; 128x128, KZ=4)
    gemm_fc2<0><<<dim3(8, 8, 4), 256, 0, stream>>>(
        bf_h, bf_l, fc1_w, nullptr, nullptr, Cp, 12544, 3136, 1024);
    fc_reduce_kernel<<<1024, 256, 0, stream>>>(Cp, fc1_b, nullptr, x1h, x1l,
                                               4, 256, 1);

    // fc2_w pre-split into dead bf region
    repack_split_kernel<<<1024, 256, 0, stream>>>(fc2_w, fc2h, fc2l);

    // K3: fc2 (all-DMA)
    gemm_fc2<1><<<dim3(8, 8, 4), 256, 0, stream>>>(
        x1h, x1l, nullptr, fc2h, fc2l, Cp, 1024, 256, 1024);
    fc_reduce_kernel<<<1024, 256, 0, stream>>>(Cp, fc2_b, nullptr, x2h, x2l,
                                               4, 256, 1);

    // K4: head GEMM: L = x2 @ Wcat^T + bcat  (M=1024, N=512, K=1024, KZ=8)
    gemm_fc2<1><<<dim3(4, 8, 8), 256, 0, stream>>>(
        x2h, x2l, nullptr, Wcat_h, Wcat_l, Cp, 1024, 128, 512);
    fc_reduce_kernel<<<512, 256, 0, stream>>>(Cp, bcat, Lh, nullptr, nullptr,
                                              8, 128, 0);

    // K5: softmax/argmax/decode from precomputed L
    heads_finish_kernel<<<RTOT, 128, 0, stream>>>(Lh, props, scores, boxes,
                                                  labels, mboxes);

    // W0: conv/deconv weight repacks (Cp now dead -> Wr/Wd alias it)
    repack_wts_kernel<<<4*9*256, 256, 0, stream>>>(mconv_w, Wr);
    repack_dw_kernel<<<1024, 256, 0, stream>>>(dconv_w, Wd);

    // K6: roi_align 14x14 -> bufA (channel-split: 8 groups)
    roi_align14_kernel<<<dim3(RMASK, 8), 256, 0, stream>>>(
        f0, f1, f2, f3, mboxes, bidx, bufA);

    // K7: 4x conv3x3 MFMA (2 co-tiles/wave), ping-pong A->B->A->B->A
    conv3x3_mfma_kernel<<<RMASK*2, 256, 0, stream>>>(bufA, Wr, mconv_b, bufB, 0);
    conv3x3_mfma_kernel<<<RMASK*2, 256, 0, stream>>>(bufB, Wr, mconv_b, bufA, 1);
    conv3x3_mfma_kernel<<<RMASK*2, 256, 0, stream>>>(bufA, Wr, mconv_b, bufB, 2);
    conv3x3_mfma_kernel<<<RMASK*2, 256, 0, stream>>>(bufB, Wr, mconv_b, bufA, 3);

    // K8: fused deconv + mask head (MFMA)
    deconv_mask_mfma_kernel<<<RMASK, 256, 0, stream>>>(bufA, Wd, dconv_b, mlog_w,
                                                       mlog_b, labels, masks);
}

// Round 5
// 830.247 us; speedup vs baseline: 1.2204x; 1.2204x over previous
//
#include <hip/hip_runtime.h>

// ---------------------------------------------------------------------------
// Mask-RCNN RoI head. Round 12:
//  - Round-11's float4+cndmask roi regressed (roi14 200us: line-split loads +
//    VGPR 116 -> 17% occupancy -> latency exposed). Reverted to round-10
//    float2 gather form as FALLBACK.
//  - Root cause of roi cost is NCHW scatter: every tap x channel is its own
//    transaction. NEW: NCHW->NHWC transpose of all 4 feature levels, then
//    wave-per-pixel roi kernels where ONE dwordx4 instruction fetches all 256
//    channels of a tap (16 VMEM instr/pixel, 128x fewer than gather).
//    Needs 109MB extra workspace -> guarded by ws_size >= 190MB, else the
//    gather fallback runs (round-10 behavior, ~882us).
// ---------------------------------------------------------------------------

#define NUM_CLASSES 81
#define CDIM 256
#define RTOT 1024
#define RMASK 256
#define LOG1000_16 4.135166556742356f

typedef _Float16 half8v __attribute__((ext_vector_type(8)));
typedef _Float16 half4v __attribute__((ext_vector_type(4)));
typedef float    float4v __attribute__((ext_vector_type(4)));
typedef float    float2a4 __attribute__((ext_vector_type(2), aligned(4)));

__device__ __forceinline__ void gload_lds16(const void* g, void* l) {
    __builtin_amdgcn_global_load_lds(
        (const __attribute__((address_space(1))) void*)g,
        (__attribute__((address_space(3))) void*)l, 16, 0, 0);
}

// ---------------------------------------------------------------------------
// NCHW -> NHWC transpose (per level). Tile 64ch x 64x via LDS.
// ---------------------------------------------------------------------------
__global__ __launch_bounds__(256) void transpose_nhwc_kernel(
    const float* __restrict__ in, float* __restrict__ out, int H, int W)
{
    __shared__ float tile[64][65];
    int t = threadIdx.x;
    int xl = t & 63, cq = t >> 6;
    int x0 = blockIdx.x * 64;
    int y  = blockIdx.y;
    int b  = blockIdx.z >> 2;
    int c0 = (blockIdx.z & 3) * 64;

    const float* ip = in + (((size_t)(b*CDIM + c0))*H + y)*W + x0;
    if (x0 + xl < W) {
        #pragma unroll
        for (int i = 0; i < 16; ++i) {
            int cl = cq + i*4;
            tile[cl][xl] = ip[(size_t)cl*H*W + xl];
        }
    }
    __syncthreads();
    float* op = out + (((size_t)b*H + y)*W + x0)*CDIM + c0;
    #pragma unroll
    for (int i = 0; i < 16; ++i) {
        int xw = cq + i*4;
        if (x0 + xw < W)
            op[(size_t)xw*CDIM + xl] = tile[xl][xw];
    }
}

// ---------------------------------------------------------------------------
// Shared geometry helper (per subsample axis), identical math to reference.
// ---------------------------------------------------------------------------
__device__ __forceinline__ void axis_taps(
    float start, float ext, int o, float invn, int N,
    float* wgt, int* idx)
{
    #pragma unroll
    for (int s = 0; s < 2; ++s) {
        int i = o*2 + s;
        float g = ((float)i + 0.5f) * invn;
        float c = start + ext*g;
        float mv = ((c > -1.f) && (c < (float)N)) ? 1.f : 0.f;
        float cl = fminf(fmaxf(c, 0.f), (float)(N-1));
        int   i0 = (int)fminf(floorf(cl), (float)(N-2));
        float l  = cl - (float)i0;
        wgt[s*2+0] = (1.f-l)*mv;
        wgt[s*2+1] = l*mv;
        idx[s*2+0] = i0;
        idx[s*2+1] = i0+1;
    }
}

// ---------------------------------------------------------------------------
// K1 (NHWC): roi_align 7x7. Block = roi; wave = pixel; lane = 4 channels.
// 16 coalesced dwordx4 tap loads per pixel. LDS-transposed output so the
// bf[r][c*49+p] store is coalesced.
// ---------------------------------------------------------------------------
__global__ __launch_bounds__(256) void roi_align7_nhwc_kernel(
    const float* __restrict__ fT0, const float* __restrict__ fT1,
    const float* __restrict__ fT2, const float* __restrict__ fT3,
    const float* __restrict__ props, const int* __restrict__ bidx,
    _Float16* __restrict__ bf_h, _Float16* __restrict__ bf_l)
{
    __shared__ _Float16 lh[256*49];
    __shared__ _Float16 ll[256*49];
    int r = blockIdx.x, t = threadIdx.x;
    int lane = t & 63, wv = t >> 6;

    float x1 = props[r*4+0], y1 = props[r*4+1];
    float x2 = props[r*4+2], y2 = props[r*4+3];
    float area = fmaxf(x2-x1, 0.f) * fmaxf(y2-y1, 0.f);
    float lf = floorf(4.f + log2f(sqrtf(area)/224.f + 1e-6f));
    lf = fminf(fmaxf(lf, 2.f), 5.f);
    int lvl = (int)lf - 2;

    const float* fT; int H, W; float scale;
    if (lvl == 0)      { fT = fT0; H = 200; W = 200; scale = 0.25f; }
    else if (lvl == 1) { fT = fT1; H = 100; W = 100; scale = 0.125f; }
    else if (lvl == 2) { fT = fT2; H = 50;  W = 50;  scale = 0.0625f; }
    else               { fT = fT3; H = 25;  W = 25;  scale = 0.03125f; }
    int b = bidx[r];
    const float* fb = fT + ((size_t)b*H*W)*CDIM + lane*4;

    float x1s = x1*scale, y1s = y1*scale;
    float rw = fmaxf(x2*scale - x1s, 1.f);
    float rh = fmaxf(y2*scale - y1s, 1.f);

    for (int p = wv; p < 49; p += 4) {
        int oy = p / 7, ox = p % 7;
        float uy[4]; int yr[4];
        axis_taps(y1s, rh, oy, 1.f/14.f, H, uy, yr);
        float wx[4]; int xc[4];
        axis_taps(x1s, rw, ox, 1.f/14.f, W, wx, xc);

        float a0 = 0.f, a1 = 0.f, a2 = 0.f, a3 = 0.f;
        #pragma unroll
        for (int a = 0; a < 4; ++a) {
            const float* rowp = fb + (size_t)(yr[a]*W)*CDIM;
            #pragma unroll
            for (int c2 = 0; c2 < 4; ++c2) {
                float w = uy[a]*wx[c2];
                float4v v = *(const float4v*)(rowp + xc[c2]*CDIM);
                a0 += w*v[0]; a1 += w*v[1]; a2 += w*v[2]; a3 += w*v[3];
            }
        }
        float av[4] = {a0, a1, a2, a3};
        #pragma unroll
        for (int e = 0; e < 4; ++e) {
            float vv = av[e]*0.25f;
            _Float16 h = (_Float16)vv;
            int c = lane*4 + e;
            lh[c*49 + p] = h;
            ll[c*49 + p] = (_Float16)((vv - (float)h)*2048.f);
        }
    }
    __syncthreads();
    size_t ob = (size_t)r*12544;
    for (int k = t; k < 12544; k += 256) {
        bf_h[ob + k] = lh[k];
        bf_l[ob + k] = ll[k];
    }
}

// ---------------------------------------------------------------------------
// K6 (NHWC): roi_align 14x14 -> actT[mi][p][c]. Direct coalesced half4 store.
// grid (RMASK, 4): 49 pixels per block for occupancy.
// ---------------------------------------------------------------------------
__global__ __launch_bounds__(256) void roi_align14_nhwc_kernel(
    const float* __restrict__ fT0, const float* __restrict__ fT1,
    const float* __restrict__ fT2, const float* __restrict__ fT3,
    const float* __restrict__ mboxes, const int* __restrict__ bidx,
    _Float16* __restrict__ outT)
{
    int mi = blockIdx.x, py = blockIdx.y;
    int t = threadIdx.x;
    int lane = t & 63, wv = t >> 6;

    float x1 = mboxes[mi*4+0], y1 = mboxes[mi*4+1];
    float x2 = mboxes[mi*4+2], y2 = mboxes[mi*4+3];
    float area = fmaxf(x2-x1, 0.f) * fmaxf(y2-y1, 0.f);
    float lf = floorf(4.f + log2f(sqrtf(area)/224.f + 1e-6f));
    lf = fminf(fmaxf(lf, 2.f), 5.f);
    int lvl = (int)lf - 2;

    const float* fT; int H, W; float scale;
    if (lvl == 0)      { fT = fT0; H = 200; W = 200; scale = 0.25f; }
    else if (lvl == 1) { fT = fT1; H = 100; W = 100; scale = 0.125f; }
    else if (lvl == 2) { fT = fT2; H = 50;  W = 50;  scale = 0.0625f; }
    else               { fT = fT3; H = 25;  W = 25;  scale = 0.03125f; }
    int ridx = (mi < 128) ? mi : mi + 384;
    int b = bidx[ridx];
    const float* fb = fT + ((size_t)b*H*W)*CDIM + lane*4;

    float x1s = x1*scale, y1s = y1*scale;
    float rw = fmaxf(x2*scale - x1s, 1.f);
    float rh = fmaxf(y2*scale - y1s, 1.f);

    for (int pp = wv; pp < 49; pp += 4) {
        int p = py*49 + pp;
        int oy = p / 14, ox = p % 14;
        float uy[4]; int yr[4];
        axis_taps(y1s, rh, oy, 1.f/28.f, H, uy, yr);
        float wx[4]; int xc[4];
        axis_taps(x1s, rw, ox, 1.f/28.f, W, wx, xc);

        float a0 = 0.f, a1 = 0.f, a2 = 0.f, a3 = 0.f;
        #pragma unroll
        for (int a = 0; a < 4; ++a) {
            const float* rowp = fb + (size_t)(yr[a]*W)*CDIM;
            #pragma unroll
            for (int c2 = 0; c2 < 4; ++c2) {
                float w = uy[a]*wx[c2];
                float4v v = *(const float4v*)(rowp + xc[c2]*CDIM);
                a0 += w*v[0]; a1 += w*v[1]; a2 += w*v[2]; a3 += w*v[3];
            }
        }
        half4v hv;
        hv[0] = (_Float16)(a0*0.25f);
        hv[1] = (_Float16)(a1*0.25f);
        hv[2] = (_Float16)(a2*0.25f);
        hv[3] = (_Float16)(a3*0.25f);
        *(half4v*)(outT + ((size_t)mi*196 + p)*CDIM + lane*4) = hv;
    }
}

// ---------------------------------------------------------------------------
// K1 fallback (gather, round-10 form): roi_align 7x7, float2 tap pairs.
// ---------------------------------------------------------------------------
__global__ __launch_bounds__(256) void roi_align7_kernel(
    const float* __restrict__ f0, const float* __restrict__ f1,
    const float* __restrict__ f2, const float* __restrict__ f3,
    const float* __restrict__ props, const int* __restrict__ bidx,
    _Float16* __restrict__ bf_h, _Float16* __restrict__ bf_l)
{
    int r  = blockIdx.x;
    int cg = blockIdx.y;
    int t = threadIdx.x;
    if (t >= 196) return;
    int p  = t % 49;
    int cl = t / 49;
    int oy = p / 7, ox = p % 7;

    float x1 = props[r*4+0], y1 = props[r*4+1];
    float x2 = props[r*4+2], y2 = props[r*4+3];
    float area = fmaxf(x2-x1, 0.f) * fmaxf(y2-y1, 0.f);
    float lf = floorf(4.f + log2f(sqrtf(area)/224.f + 1e-6f));
    lf = fminf(fmaxf(lf, 2.f), 5.f);
    int lvl = (int)lf - 2;

    const float* feat; int H, W; float scale;
    if (lvl == 0)      { feat = f0; H = 200; W = 200; scale = 0.25f; }
    else if (lvl == 1) { feat = f1; H = 100; W = 100; scale = 0.125f; }
    else if (lvl == 2) { feat = f2; H = 50;  W = 50;  scale = 0.0625f; }
    else               { feat = f3; H = 25;  W = 25;  scale = 0.03125f; }
    int b = bidx[r];

    float x1s = x1*scale, y1s = y1*scale;
    float rw = fmaxf(x2*scale - x1s, 1.f);
    float rh = fmaxf(y2*scale - y1s, 1.f);

    int   offs[4];
    float w00[4], w01[4], w10[4], w11[4];
    #pragma unroll
    for (int sy = 0; sy < 2; ++sy) {
        int iy = oy*2 + sy;
        float gy = ((float)iy + 0.5f) / 14.f;
        float yc = y1s + rh*gy;
        bool  yv = (yc > -1.f) && (yc < (float)H);
        float ycl = fminf(fmaxf(yc, 0.f), (float)(H-1));
        int   y0  = (int)fminf(floorf(ycl), (float)(H-2));
        float ly  = ycl - (float)y0;
        #pragma unroll
        for (int sx = 0; sx < 2; ++sx) {
            int ix = ox*2 + sx;
            float gx = ((float)ix + 0.5f) / 14.f;
            float xc = x1s + rw*gx;
            bool  xv = (xc > -1.f) && (xc < (float)W);
            float xcl = fminf(fmaxf(xc, 0.f), (float)(W-1));
            int   x0  = (int)fminf(floorf(xcl), (float)(W-2));
            float lx  = xcl - (float)x0;
            float m = (yv && xv) ? 1.f : 0.f;
            int s = sy*2 + sx;
            offs[s] = y0*W + x0;
            w00[s] = (1.f-ly)*(1.f-lx)*m;
            w01[s] = (1.f-ly)*lx*m;
            w10[s] = ly*(1.f-lx)*m;
            w11[s] = ly*lx*m;
        }
    }

    size_t HW = (size_t)H * W;
    #pragma unroll 4
    for (int k = 0; k < 16; ++k) {
        int c = cg*64 + cl + k*4;
        const float* fb = feat + ((size_t)b*CDIM + c) * HW;
        float acc = 0.f;
        #pragma unroll
        for (int s = 0; s < 4; ++s) {
            const float* q = fb + offs[s];
            float2a4 u = *(const float2a4*)q;
            float2a4 v = *(const float2a4*)(q + W);
            acc += w00[s]*u.x + w01[s]*u.y + w10[s]*v.x + w11[s]*v.y;
        }
        float v = acc * 0.25f;
        _Float16 h = (_Float16)v;
        size_t o = (size_t)r*12544 + c*49 + p;
        bf_h[o] = h;
        bf_l[o] = (_Float16)((v - (float)h) * 2048.f);
    }
}

// ---------------------------------------------------------------------------
// K2/K3/K4: split-fp16 MFMA GEMM (round-10 counted-vmcnt pipeline, unchanged).
// ---------------------------------------------------------------------------
template<int BMODE>
__global__ __launch_bounds__(256, 1) void gemm_fc2(
    const _Float16* __restrict__ Ah, const _Float16* __restrict__ Al,
    const float* __restrict__ B32,
    const _Float16* __restrict__ Bh16, const _Float16* __restrict__ Bl16,
    float* __restrict__ Cp, int K, int KS, int NS)
{
    __shared__ __align__(16) char smem[3*32768];

    int t = threadIdx.x;
    int lane = t & 63, wave = t >> 6;
    int wm = wave >> 1, wn = wave & 1;
    int ln = lane & 15, q = lane >> 4;

    int gx = gridDim.x, gy = gridDim.y;
    int lin = blockIdx.x + gx*(blockIdx.y + gy*blockIdx.z);
    int per = (gx*gy*(int)gridDim.z) >> 3;
    int nl  = (lin & 7)*per + (lin >> 3);
    int bn  = nl % gx;
    int tmp = nl / gx;
    int bm  = tmp % gy;
    int kz  = tmp / gy;

    size_t kbase = (size_t)kz * KS;
    int asub = lane >> 2;
    int achk = (lane & 3) ^ ((lane >> 3) & 3);

    const _Float16* Agh0 = Ah + (size_t)(bm*128 + wave*32 + asub)*K + kbase + achk*8;
    const _Float16* Agh1 = Agh0 + (size_t)16*K;
    const _Float16* Agl0 = Al + (size_t)(bm*128 + wave*32 + asub)*K + kbase + achk*8;
    const _Float16* Agl1 = Agl0 + (size_t)16*K;
    int adst0 = (wave*32 + 0)*32;
    int adst1 = (wave*32 + 16)*32;

    const _Float16 *Bgh0=nullptr, *Bgh1=nullptr, *Bgl0=nullptr, *Bgl1=nullptr;
    const float *Bg0=nullptr, *Bg1=nullptr, *Bg2=nullptr, *Bg3=nullptr;
    int fdst0 = 0;
    if constexpr (BMODE == 1) {
        Bgh0 = Bh16 + (size_t)(bn*128 + wave*32 + asub)*K + kbase + achk*8;
        Bgh1 = Bgh0 + (size_t)16*K;
        Bgl0 = Bl16 + (size_t)(bn*128 + wave*32 + asub)*K + kbase + achk*8;
        Bgl1 = Bgl0 + (size_t)16*K;
    } else {
        int br8  = lane >> 3;
        int bchk = (lane & 7) ^ br8;
        const float* base = B32 + (size_t)(bn*128 + wave*32 + br8)*K + kbase + bchk*4;
        Bg0 = base;
        Bg1 = base + (size_t)8*K;
        Bg2 = base + (size_t)16*K;
        Bg3 = base + (size_t)24*K;
        fdst0 = (wave*32)*32;
    }

    auto AhB = [&](int b){ return (_Float16*)(smem + b*32768); };
    auto AlB = [&](int b){ return (_Float16*)(smem + b*32768 + 8192); };
    auto BhB = [&](int b){ return (_Float16*)(smem + b*32768 + 16384); };
    auto BlB = [&](int b){ return (_Float16*)(smem + b*32768 + 24576); };
    auto BfB = [&](int b){ return (float*)   (smem + b*32768 + 16384); };

    auto dma = [&](int k0, int b) {
        gload_lds16(Agh0 + k0, AhB(b) + adst0);
        gload_lds16(Agh1 + k0, AhB(b) + adst1);
        gload_lds16(Agl0 + k0, AlB(b) + adst0);
        gload_lds16(Agl1 + k0, AlB(b) + adst1);
        if constexpr (BMODE == 1) {
            gload_lds16(Bgh0 + k0, BhB(b) + adst0);
            gload_lds16(Bgh1 + k0, BhB(b) + adst1);
            gload_lds16(Bgl0 + k0, BlB(b) + adst0);
            gload_lds16(Bgl1 + k0, BlB(b) + adst1);
        } else {
            gload_lds16(Bg0 + k0, BfB(b) + fdst0);
            gload_lds16(Bg1 + k0, BfB(b) + fdst0 + 8*32);
            gload_lds16(Bg2 + k0, BfB(b) + fdst0 + 16*32);
            gload_lds16(Bg3 + k0, BfB(b) + fdst0 + 24*32);
        }
    };

    float4v acc1[4][4], acc2[4][4];
    #pragma unroll
    for (int i = 0; i < 4; ++i)
        #pragma unroll
        for (int j = 0; j < 4; ++j) {
            acc1[i][j] = (float4v){0.f,0.f,0.f,0.f};
            acc2[i][j] = (float4v){0.f,0.f,0.f,0.f};
        }

    int cq = (q ^ ((ln >> 1) & 3)) * 8;

    auto compute = [&](int b) {
        const _Float16* ah = AhB(b);
        const _Float16* al = AlB(b);
        half8v afh[4], afl[4], bfh[4], bfl[4];
        #pragma unroll
        for (int i = 0; i < 4; ++i) {
            int ra = (wm*64 + i*16 + ln)*32 + cq;
            afh[i] = *(const half8v*)&ah[ra];
            afl[i] = *(const half8v*)&al[ra];
        }
        if constexpr (BMODE == 1) {
            const _Float16* bh = BhB(b);
            const _Float16* bl = BlB(b);
            #pragma unroll
            for (int j = 0; j < 4; ++j) {
                int rb = (wn*64 + j*16 + ln)*32 + cq;
                bfh[j] = *(const half8v*)&bh[rb];
                bfl[j] = *(const half8v*)&bl[rb];
            }
        } else {
            const float* bfp = BfB(b);
            #pragma unroll
            for (int j = 0; j < 4; ++j) {
                int row = wn*64 + j*16 + ln;
                int c0 = (q*2)   ^ (row & 7);
                int c1 = (q*2+1) ^ (row & 7);
                float4v f0 = *(const float4v*)&bfp[row*32 + c0*4];
                float4v f1 = *(const float4v*)&bfp[row*32 + c1*4];
                #pragma unroll
                for (int e = 0; e < 4; ++e) {
                    _Float16 h0 = (_Float16)f0[e];
                    bfh[j][e] = h0;
                    bfl[j][e] = (_Float16)((f0[e] - (float)h0) * 2048.f);
                    _Float16 h1 = (_Float16)f1[e];
                    bfh[j][4+e] = h1;
                    bfl[j][4+e] = (_Float16)((f1[e] - (float)h1) * 2048.f);
                }
            }
        }
        #pragma unroll
        for (int i = 0; i < 4; ++i) {
            #pragma unroll
            for (int j = 0; j < 4; ++j) {
                acc1[i][j] = __builtin_amdgcn_mfma_f32_16x16x32_f16(
                    afh[i], bfh[j], acc1[i][j], 0, 0, 0);
                acc2[i][j] = __builtin_amdgcn_mfma_f32_16x16x32_f16(
                    afh[i], bfl[j], acc2[i][j], 0, 0, 0);
                acc2[i][j] = __builtin_amdgcn_mfma_f32_16x16x32_f16(
                    afl[i], bfh[j], acc2[i][j], 0, 0, 0);
            }
        }
    };

    int NT = KS / 32;
    dma(0, 0);
    if (NT > 1) dma(32, 1);

    for (int tt = 0; tt < NT; ++tt) {
        if (tt < NT-1) asm volatile("s_waitcnt vmcnt(8)" ::: "memory");
        else           asm volatile("s_waitcnt vmcnt(0)" ::: "memory");
        __builtin_amdgcn_s_barrier();
        asm volatile("" ::: "memory");
        if (tt + 2 < NT) dma((tt+2)*32, (tt+2)%3);
        compute(tt%3);
    }

    float* Cpz = Cp + (size_t)kz*1024*NS;
    #pragma unroll
    for (int i = 0; i < 4; ++i) {
        #pragma unroll
        for (int j = 0; j < 4; ++j) {
            int col = bn*128 + wn*64 + j*16 + ln;
            #pragma unroll
            for (int reg = 0; reg < 4; ++reg) {
                int row = bm*128 + wm*64 + i*16 + q*4 + reg;
                Cpz[(size_t)row*NS + col] =
                    acc1[i][j][reg] + acc2[i][j][reg] * (1.f/2048.f);
            }
        }
    }
}

// reduce nparts split-K partials + bias (+optional relu).
__global__ __launch_bounds__(256) void fc_reduce_kernel(
    const float* __restrict__ Cp, const float* __restrict__ bias,
    float* __restrict__ out, _Float16* __restrict__ outh,
    _Float16* __restrict__ outl, int nparts, int ns4, int do_relu)
{
    int i = blockIdx.x*256 + threadIdx.x;
    const float4* p = (const float4*)Cp;
    int pstride = 1024*ns4;
    float sx = 0.f, sy = 0.f, sz = 0.f, sw = 0.f;
    for (int j = 0; j < nparts; ++j) {
        float4 s = p[i + j*pstride];
        sx += s.x; sy += s.y; sz += s.z; sw += s.w;
    }
    float4 b4 = ((const float4*)bias)[i & (ns4-1)];
    float4 v;
    v.x = sx + b4.x; v.y = sy + b4.y; v.z = sz + b4.z; v.w = sw + b4.w;
    if (do_relu) {
        v.x = fmaxf(v.x, 0.f); v.y = fmaxf(v.y, 0.f);
        v.z = fmaxf(v.z, 0.f); v.w = fmaxf(v.w, 0.f);
    }
    if (out) ((float4*)out)[i] = v;
    if (outh) {
        float vv[4] = {v.x, v.y, v.z, v.w};
        half4v hh, hl;
        #pragma unroll
        for (int c2 = 0; c2 < 4; ++c2) {
            _Float16 h = (_Float16)vv[c2];
            hh[c2] = h;
            hl[c2] = (_Float16)((vv[c2] - (float)h) * 2048.f);
        }
        ((half4v*)outh)[i] = hh;
        ((half4v*)outl)[i] = hl;
    }
}

// generic fp32 -> fp16 h/l pre-split
__global__ __launch_bounds__(256) void repack_split_kernel(
    const float* __restrict__ w, _Float16* __restrict__ h,
    _Float16* __restrict__ l)
{
    int i = blockIdx.x*256 + threadIdx.x;
    float4 v = ((const float4*)w)[i];
    float vv[4] = {v.x, v.y, v.z, v.w};
    half4v hh, hl;
    #pragma unroll
    for (int c2 = 0; c2 < 4; ++c2) {
        _Float16 hj = (_Float16)vv[c2];
        hh[c2] = hj;
        hl[c2] = (_Float16)((vv[c2] - (float)hj) * 2048.f);
    }
    ((half4v*)h)[i] = hh;
    ((half4v*)l)[i] = hl;
}

// ---------------------------------------------------------------------------
// Head weight concat, pre-split fp16 hi/lo.
// ---------------------------------------------------------------------------
__global__ __launch_bounds__(256) void repack_head_kernel(
    const float* __restrict__ cls_w, const float* __restrict__ cls_b,
    const float* __restrict__ bbox_w, const float* __restrict__ bbox_b,
    _Float16* __restrict__ Wcat_h, _Float16* __restrict__ Wcat_l,
    float* __restrict__ bcat)
{
    int i = blockIdx.x*256 + threadIdx.x;
    int row = i >> 10, col = i & 1023;
    float v = 0.f;
    if (row < 81) v = cls_w[row*1024 + col];
    else if (row < 405) v = bbox_w[(row-81)*1024 + col];
    _Float16 h = (_Float16)v;
    Wcat_h[i] = h;
    Wcat_l[i] = (_Float16)((v - (float)h) * 2048.f);
    if (i < 512) {
        float bv = 0.f;
        if (i < 81) bv = cls_b[i];
        else if (i < 405) bv = bbox_b[i-81];
        bcat[i] = bv;
    }
}

// ---------------------------------------------------------------------------
// heads_finish: softmax/argmax/decode from precomputed L[1024][512].
// ---------------------------------------------------------------------------
__global__ __launch_bounds__(128) void heads_finish_kernel(
    const float* __restrict__ L, const float* __restrict__ props,
    float* __restrict__ scores, float* __restrict__ boxes,
    int* __restrict__ labels, float* __restrict__ mboxes)
{
    __shared__ float lg[NUM_CLASSES];
    __shared__ float red[2];
    __shared__ int slab;
    int r = blockIdx.x, t = threadIdx.x;
    const float* Lr = L + (size_t)r*512;
    if (t < NUM_CLASSES) lg[t] = Lr[t];
    __syncthreads();
    if (t == 0) {
        float mx = lg[0];
        for (int j = 1; j < NUM_CLASSES; ++j) mx = fmaxf(mx, lg[j]);
        red[0] = mx;
    }
    __syncthreads();
    float mx = red[0];
    if (t < NUM_CLASSES) lg[t] = expf(lg[t] - mx);
    __syncthreads();
    if (t == 0) {
        float s = 0.f;
        int best = 1; float bv = lg[1];
        for (int j = 0; j < NUM_CLASSES; ++j) {
            s += lg[j];
            if (j >= 1 && lg[j] > bv) { bv = lg[j]; best = j; }
        }
        red[1] = 1.f/s;
        slab = best;
    }
    __syncthreads();
    if (t < NUM_CLASSES) scores[(size_t)r*NUM_CLASSES + t] = lg[t]*red[1];

    bool sel = (r < 128) || (r >= 512 && r < 640);
    int mi = (r < 128) ? r : r - 384;
    if (t == 0 && sel) labels[mi] = slab;

    if (t < NUM_CLASSES) {
        float px1 = props[r*4+0], py1 = props[r*4+1];
        float px2 = props[r*4+2], py2 = props[r*4+3];
        float pw = px2 - px1, ph = py2 - py1;
        float cx = px1 + 0.5f*pw, cy = py1 + 0.5f*ph;
        const float* dl = Lr + 81 + t*4;
        float d0 = dl[0] * 0.1f;
        float d1 = dl[1] * 0.1f;
        float d2 = fminf(dl[2] * 0.2f, LOG1000_16);
        float d3 = fminf(dl[3] * 0.2f, LOG1000_16);
        float pcx = d0*pw + cx, pcy = d1*ph + cy;
        float qw = expf(d2)*pw, qh = expf(d3)*ph;
        float b0 = fminf(fmaxf(pcx - 0.5f*qw, 0.f), 800.f);
        float b1 = fminf(fmaxf(pcy - 0.5f*qh, 0.f), 800.f);
        float b2 = fminf(fmaxf(pcx + 0.5f*qw, 0.f), 800.f);
        float b3 = fminf(fmaxf(pcy + 0.5f*qh, 0.f), 800.f);
        size_t ob = ((size_t)r*NUM_CLASSES + t)*4;
        boxes[ob+0] = b0; boxes[ob+1] = b1; boxes[ob+2] = b2; boxes[ob+3] = b3;
        if (sel && t == slab) {
            mboxes[mi*4+0] = b0; mboxes[mi*4+1] = b1;
            mboxes[mi*4+2] = b2; mboxes[mi*4+3] = b3;
        }
    }
}

// ---------------------------------------------------------------------------
// K6 fallback (gather, round-10 form): roi_align 14x14.
// ---------------------------------------------------------------------------
__global__ __launch_bounds__(256) void roi_align14_kernel(
    const float* __restrict__ f0, const float* __restrict__ f1,
    const float* __restrict__ f2, const float* __restrict__ f3,
    const float* __restrict__ mboxes, const int* __restrict__ bidx,
    _Float16* __restrict__ outT)
{
    int mi = blockIdx.x;
    int cg = blockIdx.y;
    int t = threadIdx.x;
    if (t >= 196) return;
    int oy = t / 14, ox = t % 14;

    float x1 = mboxes[mi*4+0], y1 = mboxes[mi*4+1];
    float x2 = mboxes[mi*4+2], y2 = mboxes[mi*4+3];
    float area = fmaxf(x2-x1, 0.f) * fmaxf(y2-y1, 0.f);
    float lf = floorf(4.f + log2f(sqrtf(area)/224.f + 1e-6f));
    lf = fminf(fmaxf(lf, 2.f), 5.f);
    int lvl = (int)lf - 2;

    const float* feat; int H, W; float scale;
    if (lvl == 0)      { feat = f0; H = 200; W = 200; scale = 0.25f; }
    else if (lvl == 1) { feat = f1; H = 100; W = 100; scale = 0.125f; }
    else if (lvl == 2) { feat = f2; H = 50;  W = 50;  scale = 0.0625f; }
    else               { feat = f3; H = 25;  W = 25;  scale = 0.03125f; }
    int ridx = (mi < 128) ? mi : mi + 384;
    int b = bidx[ridx];

    float x1s = x1*scale, y1s = y1*scale;
    float rw = fmaxf(x2*scale - x1s, 1.f);
    float rh = fmaxf(y2*scale - y1s, 1.f);

    int   offs[4];
    float w00[4], w01[4], w10[4], w11[4];
    #pragma unroll
    for (int sy = 0; sy < 2; ++sy) {
        int iy = oy*2 + sy;
        float gy = ((float)iy + 0.5f) / 28.f;
        float yc = y1s + rh*gy;
        bool  yv = (yc > -1.f) && (yc < (float)H);
        float ycl = fminf(fmaxf(yc, 0.f), (float)(H-1));
        int   y0  = (int)fminf(floorf(ycl), (float)(H-2));
        float ly  = ycl - (float)y0;
        #pragma unroll
        for (int sx = 0; sx < 2; ++sx) {
            int ix = ox*2 + sx;
            float gx = ((float)ix + 0.5f) / 28.f;
            float xc = x1s + rw*gx;
            bool  xv = (xc > -1.f) && (xc < (float)W);
            float xcl = fminf(fmaxf(xc, 0.f), (float)(W-1));
            int   x0  = (int)fminf(floorf(xcl), (float)(W-2));
            float lx  = xcl - (float)x0;
            float m = (yv && xv) ? 1.f : 0.f;
            int s = sy*2 + sx;
            offs[s] = y0*W + x0;
            w00[s] = (1.f-ly)*(1.f-lx)*m;
            w01[s] = (1.f-ly)*lx*m;
            w10[s] = ly*(1.f-lx)*m;
            w11[s] = ly*lx*m;
        }
    }

    size_t HW = (size_t)H * W;
    _Float16* orow = outT + ((size_t)mi*196 + t)*CDIM + cg*32;
    const float* fbase = feat + ((size_t)b*CDIM + cg*32) * HW;
    #pragma unroll
    for (int c8 = 0; c8 < 32; c8 += 8) {
        half8v hv;
        #pragma unroll
        for (int cc = 0; cc < 8; ++cc) {
            const float* fb = fbase + (size_t)(c8+cc) * HW;
            float acc = 0.f;
            #pragma unroll
            for (int s = 0; s < 4; ++s) {
                const float* q = fb + offs[s];
                float2a4 u = *(const float2a4*)q;
                float2a4 v = *(const float2a4*)(q + W);
                acc += w00[s]*u.x + w01[s]*u.y + w10[s]*v.x + w11[s]*v.y;
            }
            hv[cc] = (_Float16)(acc * 0.25f);
        }
        *(half8v*)(orow + c8) = hv;
    }
}

// ---------------------------------------------------------------------------
// Weight repacks (conv / deconv)
// ---------------------------------------------------------------------------
__global__ __launch_bounds__(256) void repack_wts_kernel(
    const float* __restrict__ w, _Float16* __restrict__ Wr)
{
    int i = blockIdx.x*256 + threadIdx.x;
    int ci = i & 255;
    int rest = i >> 8;
    int co = rest & 255;
    int rest2 = rest >> 8;
    int tap = rest2 % 9;
    int l = rest2 / 9;
    Wr[i] = (_Float16)w[(((size_t)(l*256 + co)*256 + ci)*9) + tap];
}

__global__ __launch_bounds__(256) void repack_dw_kernel(
    const float* __restrict__ dw, _Float16* __restrict__ Wd)
{
    int i = blockIdx.x*256 + threadIdx.x;
    int n = i >> 8, k = i & 255;
    Wd[i] = (_Float16)dw[(size_t)k*1024 + n];
}

// ---------------------------------------------------------------------------
// K7: conv3x3+bias+relu as fp16 MFMA implicit GEMM, 2 co-tiles per wave.
// ---------------------------------------------------------------------------
#define PSTR 40

__global__ __launch_bounds__(256, 2) void conv3x3_mfma_kernel(
    const _Float16* __restrict__ inT, const _Float16* __restrict__ Wr,
    const float* __restrict__ bias, _Float16* __restrict__ outT, int layer)
{
    __shared__ _Float16 lin[256*PSTR];

    int t = threadIdx.x;
    int lane = t & 63;
    int wave = t >> 6;
    int ln = lane & 15;
    int q  = lane >> 4;
    int q8 = q*8;
    int r  = blockIdx.x >> 1;
    int bc = blockIdx.x & 1;
    int co_w = bc*128 + wave*32;

    const _Float16* WrL = Wr + (size_t)layer*9*256*256;
    const _Float16* inR = inT + (size_t)r*196*256;

    for (int i = t; i < 256*PSTR; i += 256) lin[i] = (_Float16)0.f;

    float4v acc[13][2];
    #pragma unroll
    for (int nt = 0; nt < 13; ++nt) {
        acc[nt][0] = (float4v){0.f,0.f,0.f,0.f};
        acc[nt][1] = (float4v){0.f,0.f,0.f,0.f};
    }

    for (int ci0 = 0; ci0 < 256; ci0 += 32) {
        __syncthreads();
        for (int idx = t; idx < 784; idx += 256) {
            int p = idx >> 2, g = idx & 3;
            float4 v = *(const float4*)(inR + (size_t)p*256 + ci0 + g*8);
            int row = (p*37450) >> 19;
            int col = p - row*14;
            *(float4*)&lin[((row+1)*16 + (col+1))*PSTR + g*8] = v;
        }
        __syncthreads();

        half8v aw[9][2];
        #pragma unroll
        for (int tap = 0; tap < 9; ++tap) {
            #pragma unroll
            for (int u = 0; u < 2; ++u)
                aw[tap][u] = *(const half8v*)(
                    WrL + ((size_t)tap*256 + co_w + u*16 + ln)*256 + ci0 + q8);
        }

        #pragma unroll
        for (int nt = 0; nt < 13; ++nt) {
            int n = nt*16 + ln;
            int row = (n*37450) >> 19;
            int col = n - row*14;
            int pb = (n < 196) ? (row*16 + col) : 0;
            const _Float16* bp = &lin[pb*PSTR + q8];
            #pragma unroll
            for (int ky = 0; ky < 3; ++ky) {
                #pragma unroll
                for (int kx = 0; kx < 3; ++kx) {
                    half8v bv = *(const half8v*)(bp + (ky*16 + kx)*PSTR);
                    acc[nt][0] = __builtin_amdgcn_mfma_f32_16x16x32_f16(
                        aw[ky*3+kx][0], bv, acc[nt][0], 0, 0, 0);
                    acc[nt][1] = __builtin_amdgcn_mfma_f32_16x16x32_f16(
                        aw[ky*3+kx][1], bv, acc[nt][1], 0, 0, 0);
                }
            }
        }
    }

    #pragma unroll
    for (int u = 0; u < 2; ++u) {
        float4 bi = *(const float4*)&bias[layer*256 + co_w + u*16 + q*4];
        float bia[4] = {bi.x, bi.y, bi.z, bi.w};
        #pragma unroll
        for (int nt = 0; nt < 13; ++nt) {
            int n = nt*16 + ln;
            if (n < 196) {
                half4v hv;
                #pragma unroll
                for (int i = 0; i < 4; ++i)
                    hv[i] = (_Float16)fmaxf(acc[nt][u][i] + bia[i], 0.f);
                *(half4v*)(outT + ((size_t)r*196 + n)*256 + co_w + u*16 + q*4) = hv;
            }
        }
    }
}

// ---------------------------------------------------------------------------
// K8: deconv+mask head, fp16 MFMA per-roi GEMM with fused epilogue.
// ---------------------------------------------------------------------------
#define DSTR 264

template<int NMT>
__device__ __forceinline__ void deconv_pass(
    const _Float16* actL, const _Float16* __restrict__ Wd,
    const float* __restrict__ db, const float* __restrict__ mlw,
    int lab, float (*sred)[4], int wv, int ln, int q, int px0)
{
    float P[NMT][4];
    #pragma unroll
    for (int mt = 0; mt < NMT; ++mt)
        #pragma unroll
        for (int r2 = 0; r2 < 4; ++r2) P[mt][r2] = 0.f;

    for (int c = 0; c < 8; ++c) {
        int n0 = wv*256 + c*32;
        float4v acc[NMT][2];
        #pragma unroll
        for (int mt = 0; mt < NMT; ++mt) {
            acc[mt][0] = (float4v){0.f,0.f,0.f,0.f};
            acc[mt][1] = (float4v){0.f,0.f,0.f,0.f};
        }
        #pragma unroll
        for (int k = 0; k < 8; ++k) {
            const _Float16* wp = Wd + ((size_t)(n0 + ln))*256 + k*32 + q*8;
            half8v b0 = *(const half8v*)wp;
            half8v b1 = *(const half8v*)(wp + 16*256);
            #pragma unroll
            for (int mt = 0; mt < NMT; ++mt) {
                half8v a = *(const half8v*)&actL[(mt*16 + ln)*DSTR + k*32 + q*8];
                acc[mt][0] = __builtin_amdgcn_mfma_f32_16x16x32_f16(
                    a, b0, acc[mt][0], 0, 0, 0);
                acc[mt][1] = __builtin_amdgcn_mfma_f32_16x16x32_f16(
                    a, b1, acc[mt][1], 0, 0, 0);
            }
        }
        #pragma unroll
        for (int j = 0; j < 2; ++j) {
            int n = n0 + j*16 + ln;
            int o = n >> 2;
            float bo = db[o];
            float wl = mlw[lab*256 + o];
            #pragma unroll
            for (int mt = 0; mt < NMT; ++mt)
                #pragma unroll
                for (int r2 = 0; r2 < 4; ++r2)
                    P[mt][r2] += fmaxf(acc[mt][j][r2] + bo, 0.f) * wl;
        }
    }
    #pragma unroll
    for (int mt = 0; mt < NMT; ++mt)
        #pragma unroll
        for (int r2 = 0; r2 < 4; ++r2) {
            float v = P[mt][r2];
            v += __shfl_xor(v, 4);
            v += __shfl_xor(v, 8);
            int px = px0 + mt*16 + q*4 + r2;
            if (ln < 4 && px < 196) atomicAdd(&sred[px][ln], v);
        }
}

__global__ __launch_bounds__(256, 1) void deconv_mask_mfma_kernel(
    const _Float16* __restrict__ mfT, const _Float16* __restrict__ Wd,
    const float* __restrict__ db, const float* __restrict__ mlw,
    const float* __restrict__ mlb, const int* __restrict__ labels,
    float* __restrict__ masks)
{
    __shared__ _Float16 act[112*DSTR];
    __shared__ float sred[196][4];
    int t = threadIdx.x;
    int lane = t & 63, wv = t >> 6, ln = lane & 15, q = lane >> 4;
    int mi = blockIdx.x;
    int lab = labels[mi];

    for (int i = t; i < 784; i += 256) ((float*)sred)[i] = 0.f;

    for (int idx = t; idx < 112*32; idx += 256) {
        int px = idx >> 5, g = idx & 31;
        *(float4*)&act[px*DSTR + g*8] =
            *(const float4*)(mfT + ((size_t)mi*196 + px)*256 + g*8);
    }
    __syncthreads();
    deconv_pass<7>(act, Wd, db, mlw, lab, sred, wv, ln, q, 0);
    __syncthreads();

    for (int idx = t; idx < 84*32; idx += 256) {
        int px = idx >> 5, g = idx & 31;
        *(float4*)&act[px*DSTR + g*8] =
            *(const float4*)(mfT + ((size_t)mi*196 + 112 + px)*256 + g*8);
    }
    __syncthreads();
    deconv_pass<6>(act, Wd, db, mlw, lab, sred, wv, ln, q, 112);
    __syncthreads();

    if (t < 196) {
        float bl = mlb[lab];
        int i2 = t / 14, j2 = t % 14;
        #pragma unroll
        for (int pq = 0; pq < 4; ++pq) {
            float s = sred[t][pq] + bl;
            int h = 2*i2 + (pq >> 1), w2 = 2*j2 + (pq & 1);
            masks[(size_t)mi*784 + h*28 + w2] = 1.f/(1.f + expf(-s));
        }
    }
}

// ---------------------------------------------------------------------------
extern "C" void kernel_launch(void* const* d_in, const int* in_sizes, int n_in,
                              void* d_out, int out_size, void* d_ws, size_t ws_size,
                              hipStream_t stream) {
    const float* f0      = (const float*)d_in[0];
    const float* f1      = (const float*)d_in[1];
    const float* f2      = (const float*)d_in[2];
    const float* f3      = (const float*)d_in[3];
    const float* props   = (const float*)d_in[4];
    const float* fc1_w   = (const float*)d_in[5];
    const float* fc1_b   = (const float*)d_in[6];
    const float* fc2_w   = (const float*)d_in[7];
    const float* fc2_b   = (const float*)d_in[8];
    const float* cls_w   = (const float*)d_in[9];
    const float* cls_b   = (const float*)d_in[10];
    const float* bbox_w  = (const float*)d_in[11];
    const float* bbox_b  = (const float*)d_in[12];
    const float* mconv_w = (const float*)d_in[13];
    const float* mconv_b = (const float*)d_in[14];
    const float* dconv_w = (const float*)d_in[15];
    const float* dconv_b = (const float*)d_in[16];
    const float* mlog_w  = (const float*)d_in[17];
    const float* mlog_b  = (const float*)d_in[18];
    const int*   bidx    = (const int*)d_in[19];

    // workspace layout (bytes); base region tops at 80.76MB, NHWC adds 109MB
    char* wsb = (char*)d_ws;
    _Float16* bf_h = (_Float16*)wsb;                 // [0, 25.69MB)
    _Float16* bf_l = (_Float16*)(wsb + 25690112);    // [25.69, 51.38MB)
    _Float16* fc2h = (_Float16*)wsb;                 // alias (bf dead post-fc1)
    _Float16* fc2l = (_Float16*)(wsb + 2097152);
    _Float16* bufA = (_Float16*)wsb;                 // alias: conv ping
    _Float16* bufB = (_Float16*)(wsb + 25690112);    // conv pong
    _Float16* x1h  = (_Float16*)(wsb + 51380224);    // 2MB
    _Float16* x1l  = (_Float16*)(wsb + 53477376);    // 2MB
    _Float16* x2h  = (_Float16*)(wsb + 55574528);    // 2MB
    _Float16* x2l  = (_Float16*)(wsb + 57671680);    // 2MB
    int*      labels = (int*)(wsb + 59768832);       // 4KB pad
    float*    mboxes = (float*)(wsb + 59772928);     // 8KB pad
    float*    Cp     = (float*)(wsb + 59781120);     // 16MB partials
    _Float16* Wr     = (_Float16*)(wsb + 59781120);  // alias Cp (after heads)
    _Float16* Wd     = (_Float16*)(wsb + 64499712);  // alias Cp (after heads)
    _Float16* Wcat_h = (_Float16*)(wsb + 76558336);  // 1MB
    _Float16* Wcat_l = (_Float16*)(wsb + 77606912);  // 1MB
    float*    bcat   = (float*)(wsb + 78655488);     // 2KB (pad to 4KB)
    float*    Lh     = (float*)(wsb + 78659584);     // 2MB logits+deltas
    // NHWC transposed features (guarded by ws_size)
    float*    fT0    = (float*)(wsb + 80756736);     // 81.92MB
    float*    fT1    = (float*)(wsb + 162676736);    // 20.48MB
    float*    fT2    = (float*)(wsb + 183156736);    //  5.12MB
    float*    fT3    = (float*)(wsb + 188276736);    //  1.28MB  -> end 189.56MB
    bool nhwc = (ws_size >= 189556736ull);

    float* scores = (float*)d_out;
    float* boxes  = scores + RTOT*NUM_CLASSES;
    float* masks  = boxes + RTOT*NUM_CLASSES*4;

    if (nhwc) {
        transpose_nhwc_kernel<<<dim3(4, 200, 8), 256, 0, stream>>>(f0, fT0, 200, 200);
        transpose_nhwc_kernel<<<dim3(2, 100, 8), 256, 0, stream>>>(f1, fT1, 100, 100);
        transpose_nhwc_kernel<<<dim3(1,  50, 8), 256, 0, stream>>>(f2, fT2,  50,  50);
        transpose_nhwc_kernel<<<dim3(1,  25, 8), 256, 0, stream>>>(f3, fT3,  25,  25);
        roi_align7_nhwc_kernel<<<RTOT, 256, 0, stream>>>(
            fT0, fT1, fT2, fT3, props, bidx, bf_h, bf_l);
    } else {
        roi_align7_kernel<<<dim3(RTOT, 4), 256, 0, stream>>>(
            f0, f1, f2, f3, props, bidx, bf_h, bf_l);
    }

    // head weight concat+split (independent of fc phase)
    repack_head_kernel<<<2048, 256, 0, stream>>>(cls_w, cls_b, bbox_w, bbox_b,
                                                 Wcat_h, Wcat_l, bcat);

    // K2: fc1 (A presplit DMA, B fp32 DMA + convert-on-read; 128x128, KZ=4)
    gemm_fc2<0><<<dim3(8, 8, 4), 256, 0, stream>>>(
        bf_h, bf_l, fc1_w, nullptr, nullptr, Cp, 12544, 3136, 1024);
    fc_reduce_kernel<<<1024, 256, 0, stream>>>(Cp, fc1_b, nullptr, x1h, x1l,
                                               4, 256, 1);

    // fc2_w pre-split into dead bf region
    repack_split_kernel<<<1024, 256, 0, stream>>>(fc2_w, fc2h, fc2l);

    // K3: fc2 (all-DMA)
    gemm_fc2<1><<<dim3(8, 8, 4), 256, 0, stream>>>(
        x1h, x1l, nullptr, fc2h, fc2l, Cp, 1024, 256, 1024);
    fc_reduce_kernel<<<1024, 256, 0, stream>>>(Cp, fc2_b, nullptr, x2h, x2l,
                                               4, 256, 1);

    // K4: head GEMM: L = x2 @ Wcat^T + bcat  (M=1024, N=512, K=1024, KZ=8)
    gemm_fc2<1><<<dim3(4, 8, 8), 256, 0, stream>>>(
        x2h, x2l, nullptr, Wcat_h, Wcat_l, Cp, 1024, 128, 512);
    fc_reduce_kernel<<<512, 256, 0, stream>>>(Cp, bcat, Lh, nullptr, nullptr,
                                              8, 128, 0);

    // K5: softmax/argmax/decode from precomputed L
    heads_finish_kernel<<<RTOT, 128, 0, stream>>>(Lh, props, scores, boxes,
                                                  labels, mboxes);

    // W0: conv/deconv weight repacks (Cp now dead -> Wr/Wd alias it)
    repack_wts_kernel<<<4*9*256, 256, 0, stream>>>(mconv_w, Wr);
    repack_dw_kernel<<<1024, 256, 0, stream>>>(dconv_w, Wd);

    // K6: roi_align 14x14 -> bufA
    if (nhwc) {
        roi_align14_nhwc_kernel<<<dim3(RMASK, 4), 256, 0, stream>>>(
            fT0, fT1, fT2, fT3, mboxes, bidx, bufA);
    } else {
        roi_align14_kernel<<<dim3(RMASK, 8), 256, 0, stream>>>(
            f0, f1, f2, f3, mboxes, bidx, bufA);
    }

    // K7: 4x conv3x3 MFMA (2 co-tiles/wave), ping-pong A->B->A->B->A
    conv3x3_mfma_kernel<<<RMASK*2, 256, 0, stream>>>(bufA, Wr, mconv_b, bufB, 0);
    conv3x3_mfma_kernel<<<RMASK*2, 256, 0, stream>>>(bufB, Wr, mconv_b, bufA, 1);
    conv3x3_mfma_kernel<<<RMASK*2, 256, 0, stream>>>(bufA, Wr, mconv_b, bufB, 2);
    conv3x3_mfma_kernel<<<RMASK*2, 256, 0, stream>>>(bufB, Wr, mconv_b, bufA, 3);

    // K8: fused deconv + mask head (MFMA)
    deconv_mask_mfma_kernel<<<RMASK, 256, 0, stream>>>(bufA, Wd, dconv_b, mlog_w,
                                                       mlog_b, labels, masks);
}